// Round 7
// baseline (449.997 us; speedup 1.0000x reference)
//
#include <hip/hip_runtime.h>
#include <hip/hip_bf16.h>

#define N_NODES 20000
#define N_EDGES 640000
#define D_NODE  128
#define D_EDGE  64
#define D_OUT   128

// round-to-nearest-even fp32 -> bf16 bits
__device__ __forceinline__ unsigned short f2bf(float x) {
    unsigned u = __float_as_uint(x);
    unsigned r = ((u >> 16) & 1u) + 0x7FFFu;
    return (unsigned short)((u + r) >> 16);
}
__device__ __forceinline__ float bf2f(unsigned short b) {
    return __uint_as_float((unsigned)b << 16);
}

// ---------------------------------------------------------------------------
// k_init_prep: blocks 0..78 zero deg; block 79 builds WnT + ce, zeroes ticket.
// ---------------------------------------------------------------------------
__global__ __launch_bounds__(256) void k_init_prep(const float* __restrict__ Wn,
                                                   const float* __restrict__ We,
                                                   const float* __restrict__ Wa,
                                                   int* __restrict__ deg,
                                                   float* __restrict__ WnT,
                                                   float* __restrict__ ce,
                                                   int* __restrict__ ticket) {
    int t = threadIdx.x, b = blockIdx.x;
    if (b < 79) {
        int i = b * 256 + t;
        if (i < N_NODES) deg[i] = 0;
    } else {
        for (int idx = t; idx < D_OUT * D_NODE; idx += 256) {
            int o = idx >> 7, k = idx & 127;
            WnT[k * D_OUT + o] = Wn[idx];
        }
        if (t < D_EDGE) {
            float a = 0.f;
            for (int o = 0; o < D_OUT; ++o)
                a += Wa[2 * D_OUT + o] * We[o * D_EDGE + t];
            ce[t] = a;
        }
        if (t == 200) *ticket = 0;
    }
}

// ---------------------------------------------------------------------------
// k_fused: blocks [0,625) = zgemm (bf16 z, fused fp32 ssrc/sdst);
//          blocks [625,3125) = dst histogram + rank; the LAST hist block to
//          finish (device-scope ticket) runs the exclusive scan of deg ->
//          offsets, overlapping with still-running gemm blocks.
// ---------------------------------------------------------------------------
__global__ __launch_bounds__(256) void k_fused(const float* __restrict__ feats,
                                               const float* __restrict__ wT,
                                               const float* __restrict__ Wa,
                                               const int* __restrict__ dst,
                                               unsigned short* __restrict__ zb,
                                               float* __restrict__ ssrc,
                                               float* __restrict__ sdst,
                                               int* __restrict__ deg,
                                               int* __restrict__ rank,
                                               int* __restrict__ offsets,
                                               int* __restrict__ ticket) {
    __shared__ float sW[64 * 128];
    __shared__ float sF[32 * 128];
    __shared__ int sInt[8];
    __shared__ int lastFlag;
    int t = threadIdx.x;

    if (blockIdx.x >= 625) {
        int j = (blockIdx.x - 625) * 256 + t;
        rank[j] = atomicAdd(&deg[dst[j]], 1);
        __syncthreads();              // drains the atomics (vmcnt(0) before barrier)
        if (t == 0) {
            __threadfence();
            int old = atomicAdd(ticket, 1);
            lastFlag = (old == 2499);
        }
        __syncthreads();
        if (!lastFlag) return;
        // ---- exclusive scan, 256 threads x 80 contiguous elems ----
        const int PER = 80;
        int lane = t & 63, wv = t >> 6;
        int base = t * PER;
        int tsum = 0;
        for (int i = 0; i < PER; ++i) {
            int idx = base + i;
            if (idx < N_NODES)
                tsum += __hip_atomic_load(&deg[idx], __ATOMIC_RELAXED,
                                          __HIP_MEMORY_SCOPE_AGENT);
        }
        int x = tsum;
#pragma unroll
        for (int d = 1; d < 64; d <<= 1) {
            int y = __shfl_up(x, d, 64);
            if (lane >= d) x += y;
        }
        if (lane == 63) sInt[wv] = x;
        __syncthreads();
        if (t == 0) {
            int a = 0;
            for (int i = 0; i < 4; ++i) { int tmp = sInt[i]; sInt[4 + i] = a; a += tmp; }
            offsets[N_NODES] = a;
        }
        __syncthreads();
        int run = (x - tsum) + sInt[4 + wv];
        for (int i = 0; i < PER; ++i) {
            int idx = base + i;
            if (idx < N_NODES) {
                offsets[idx] = run;
                run += __hip_atomic_load(&deg[idx], __ATOMIC_RELAXED,
                                         __HIP_MEMORY_SCOPE_AGENT);
            }
        }
        return;
    }

    int nb = blockIdx.x * 32;
    const float4* fsrc = (const float4*)(feats + (size_t)nb * D_NODE);
    float4* fdst = (float4*)sF;
    for (int i = t; i < 32 * 32; i += 256) fdst[i] = fsrc[i];

    float acc[4][4] = {{0.f}};
    int o0 = (t & 31) * 4;
    int n0 = (t >> 5) * 4;

    for (int p = 0; p < 2; ++p) {
        __syncthreads();
        const float4* wsrc = (const float4*)(wT + p * 64 * 128);
        float4* wdst = (float4*)sW;
        for (int i = t; i < 64 * 32; i += 256) wdst[i] = wsrc[i];
        __syncthreads();
        for (int kk = 0; kk < 64; kk += 4) {
            float4 w0 = *(const float4*)(sW + (kk + 0) * 128 + o0);
            float4 w1 = *(const float4*)(sW + (kk + 1) * 128 + o0);
            float4 w2 = *(const float4*)(sW + (kk + 2) * 128 + o0);
            float4 w3 = *(const float4*)(sW + (kk + 3) * 128 + o0);
#pragma unroll
            for (int j = 0; j < 4; ++j) {
                float4 f = *(const float4*)(sF + (n0 + j) * 128 + p * 64 + kk);
                acc[j][0] += f.x * w0.x + f.y * w1.x + f.z * w2.x + f.w * w3.x;
                acc[j][1] += f.x * w0.y + f.y * w1.y + f.z * w2.y + f.w * w3.y;
                acc[j][2] += f.x * w0.z + f.y * w1.z + f.z * w2.z + f.w * w3.z;
                acc[j][3] += f.x * w0.w + f.y * w1.w + f.z * w2.w + f.w * w3.w;
            }
        }
    }

    float as0 = Wa[o0 + 0], as1 = Wa[o0 + 1], as2 = Wa[o0 + 2], as3 = Wa[o0 + 3];
    float ad0 = Wa[128 + o0 + 0], ad1 = Wa[128 + o0 + 1],
          ad2 = Wa[128 + o0 + 2], ad3 = Wa[128 + o0 + 3];
#pragma unroll
    for (int j = 0; j < 4; ++j) {
        int n = nb + n0 + j;
        ushort4 zo;
        zo.x = f2bf(acc[j][0]); zo.y = f2bf(acc[j][1]);
        zo.z = f2bf(acc[j][2]); zo.w = f2bf(acc[j][3]);
        *(ushort4*)(zb + (size_t)n * D_OUT + o0) = zo;
        float ps = acc[j][0] * as0 + acc[j][1] * as1 + acc[j][2] * as2 + acc[j][3] * as3;
        float pd = acc[j][0] * ad0 + acc[j][1] * ad1 + acc[j][2] * ad2 + acc[j][3] * ad3;
#pragma unroll
        for (int off = 16; off; off >>= 1) {
            ps += __shfl_xor(ps, off, 32);
            pd += __shfl_xor(pd, off, 32);
        }
        if ((t & 31) == 0) { ssrc[n] = ps; sdst[n] = pd; }
    }
}

// ---------------------------------------------------------------------------
// k_edge: 4 threads per edge, fully coalesced; atomic-free CSR placement
// pos = offsets[dst] + rank. One 8B scatter store {e, src} per edge.
// ---------------------------------------------------------------------------
__global__ __launch_bounds__(256) void k_edge(const float* __restrict__ fe,
                                              const float* __restrict__ ce,
                                              const float* __restrict__ ssrc,
                                              const float* __restrict__ sdst,
                                              const int* __restrict__ src,
                                              const int* __restrict__ dst,
                                              const int* __restrict__ rank,
                                              const int* __restrict__ offsets,
                                              float2* __restrict__ es) {
    int t = threadIdx.x;
    int j = blockIdx.x * 64 + (t >> 2);
    int part = t & 3;
    const float4* row = (const float4*)(fe + (size_t)j * D_EDGE + part * 16);
    const float4* c4 = (const float4*)(ce + part * 16);
    float acc = 0.f;
#pragma unroll
    for (int i = 0; i < 4; ++i) {
        float4 f = row[i];
        float4 c = c4[i];
        acc += f.x * c.x + f.y * c.y + f.z * c.z + f.w * c.w;
    }
    acc += __shfl_xor(acc, 1, 64);
    acc += __shfl_xor(acc, 2, 64);
    if (part == 0) {
        int sj = src[j], dj = dst[j];
        float x = acc + ssrc[sj] + sdst[dj];
        float ev = x > 0.f ? x : 0.2f * x;
        int pos = offsets[dj] + rank[j];
        es[pos] = make_float2(ev, __int_as_float(sj));
    }
}

// ---------------------------------------------------------------------------
// k_gather: one wave per node. Softmax: lane-per-edge butterflies (no LDS,
// no barriers). Aggregation: 2 edges per wave instruction — lanes 0-31 take
// the even edge, 32-63 the odd edge, each lane loads ushort4 (4 bf16 dims);
// 8-edge unroll = 4 in-flight loads/lane; invalid edges carry weight 0 and
// row 0 (harmless). Cross-half shfl_xor(32) reduce, lanes 0-31 store float4.
// ---------------------------------------------------------------------------
__global__ __launch_bounds__(256) void k_gather(const int* __restrict__ offsets,
                                                const float2* __restrict__ es,
                                                const unsigned short* __restrict__ zb,
                                                float* __restrict__ h) {
    int lane = threadIdx.x & 63;
    int n = blockIdx.x * 4 + (threadIdx.x >> 6);
    int beg = offsets[n], end = offsets[n + 1];
    int half = lane >> 5;
    int sub = lane & 31;

    float2 v0 = make_float2(-3.4e38f, 0.f);
    int i0 = beg + lane;
    if (i0 < end) v0 = es[i0];
    float lmax = v0.x;
    for (int base = beg + 64; base < end; base += 64) {
        int i = base + lane;
        lmax = fmaxf(lmax, (i < end) ? es[i].x : -3.4e38f);
    }
#pragma unroll
    for (int off = 32; off; off >>= 1) lmax = fmaxf(lmax, __shfl_xor(lmax, off, 64));
    float m = lmax;

    float w0 = (i0 < end) ? __expf(v0.x - m) : 0.f;
    float lsum = w0;
    for (int base = beg + 64; base < end; base += 64) {
        int i = base + lane;
        lsum += (i < end) ? __expf(es[i].x - m) : 0.f;
    }
#pragma unroll
    for (int off = 32; off; off >>= 1) lsum += __shfl_xor(lsum, off, 64);
    float inv = (lsum > 0.f) ? 1.f / lsum : 0.f;

    float ax = 0.f, ay = 0.f, az = 0.f, aw = 0.f;

    // chunk 0 (weights already in registers)
    {
        int cnt = min(64, end - beg);
        float wl = w0 * inv;              // 0 for lanes >= cnt
        int sl = __float_as_int(v0.y);    // 0 for lanes >= cnt
        for (int r = 0; r < cnt; r += 8) {
            int e0 = r + half, e1 = r + 2 + half, e2 = r + 4 + half, e3 = r + 6 + half;
            float q0 = __shfl(wl, e0, 64); int s0 = __shfl(sl, e0, 64);
            float q1 = __shfl(wl, e1, 64); int s1 = __shfl(sl, e1, 64);
            float q2 = __shfl(wl, e2, 64); int s2 = __shfl(sl, e2, 64);
            float q3 = __shfl(wl, e3, 64); int s3 = __shfl(sl, e3, 64);
            ushort4 z0 = *(const ushort4*)(zb + (size_t)s0 * D_OUT + sub * 4);
            ushort4 z1 = *(const ushort4*)(zb + (size_t)s1 * D_OUT + sub * 4);
            ushort4 z2 = *(const ushort4*)(zb + (size_t)s2 * D_OUT + sub * 4);
            ushort4 z3 = *(const ushort4*)(zb + (size_t)s3 * D_OUT + sub * 4);
            ax += q0 * bf2f(z0.x) + q1 * bf2f(z1.x) + q2 * bf2f(z2.x) + q3 * bf2f(z3.x);
            ay += q0 * bf2f(z0.y) + q1 * bf2f(z1.y) + q2 * bf2f(z2.y) + q3 * bf2f(z3.y);
            az += q0 * bf2f(z0.z) + q1 * bf2f(z1.z) + q2 * bf2f(z2.z) + q3 * bf2f(z3.z);
            aw += q0 * bf2f(z0.w) + q1 * bf2f(z1.w) + q2 * bf2f(z2.w) + q3 * bf2f(z3.w);
        }
    }
    // later chunks (deg > 64)
    for (int base = beg + 64; base < end; base += 64) {
        int i = base + lane;
        float2 v = (i < end) ? es[i] : make_float2(0.f, 0.f);
        float wl = (i < end) ? __expf(v.x - m) * inv : 0.f;
        int sl = (i < end) ? __float_as_int(v.y) : 0;
        int cnt = min(64, end - base);
        for (int r = 0; r < cnt; r += 8) {
            int e0 = r + half, e1 = r + 2 + half, e2 = r + 4 + half, e3 = r + 6 + half;
            float q0 = __shfl(wl, e0, 64); int s0 = __shfl(sl, e0, 64);
            float q1 = __shfl(wl, e1, 64); int s1 = __shfl(sl, e1, 64);
            float q2 = __shfl(wl, e2, 64); int s2 = __shfl(sl, e2, 64);
            float q3 = __shfl(wl, e3, 64); int s3 = __shfl(sl, e3, 64);
            ushort4 z0 = *(const ushort4*)(zb + (size_t)s0 * D_OUT + sub * 4);
            ushort4 z1 = *(const ushort4*)(zb + (size_t)s1 * D_OUT + sub * 4);
            ushort4 z2 = *(const ushort4*)(zb + (size_t)s2 * D_OUT + sub * 4);
            ushort4 z3 = *(const ushort4*)(zb + (size_t)s3 * D_OUT + sub * 4);
            ax += q0 * bf2f(z0.x) + q1 * bf2f(z1.x) + q2 * bf2f(z2.x) + q3 * bf2f(z3.x);
            ay += q0 * bf2f(z0.y) + q1 * bf2f(z1.y) + q2 * bf2f(z2.y) + q3 * bf2f(z3.y);
            az += q0 * bf2f(z0.z) + q1 * bf2f(z1.z) + q2 * bf2f(z2.z) + q3 * bf2f(z3.z);
            aw += q0 * bf2f(z0.w) + q1 * bf2f(z1.w) + q2 * bf2f(z2.w) + q3 * bf2f(z3.w);
        }
    }
    // combine halves (both hold the same 4 dims for different edge subsets)
    ax += __shfl_xor(ax, 32, 64);
    ay += __shfl_xor(ay, 32, 64);
    az += __shfl_xor(az, 32, 64);
    aw += __shfl_xor(aw, 32, 64);
    if (half == 0)
        *(float4*)(h + (size_t)n * D_OUT + sub * 4) = make_float4(ax, ay, az, aw);
}

extern "C" void kernel_launch(void* const* d_in, const int* in_sizes, int n_in,
                              void* d_out, int out_size, void* d_ws, size_t ws_size,
                              hipStream_t stream) {
    const float* feats_node = (const float*)d_in[0];
    const float* feats_edge = (const float*)d_in[1];
    const float* Wn = (const float*)d_in[2];
    const float* We = (const float*)d_in[3];
    const float* Wa = (const float*)d_in[4];
    const int* src = (const int*)d_in[5];
    const int* dst = (const int*)d_in[6];
    float* h = (float*)d_out;

    // workspace layout
    float* WnT  = (float*)d_ws;                       // 16384 f
    float* ce   = WnT + 16384;                        // 64 f
    float* ssrc = ce + 64;                            // 20000 f
    float* sdst = ssrc + N_NODES;                     // 20000 f
    float2* es  = (float2*)(sdst + N_NODES);          // 640000 float2 (8B-aligned)
    unsigned short* zb = (unsigned short*)(es + N_EDGES); // 2,560,000 ushort
    int* deg     = (int*)(zb + (size_t)N_NODES * D_OUT);  // 20000
    int* offsets = deg + N_NODES;                     // 20001
    int* rank    = offsets + N_NODES + 1;             // 640000
    int* ticket  = rank + N_EDGES;                    // 1

    k_init_prep<<<80, 256, 0, stream>>>(Wn, We, Wa, deg, WnT, ce, ticket);
    k_fused<<<3125, 256, 0, stream>>>(feats_node, WnT, Wa, dst, zb, ssrc, sdst,
                                      deg, rank, offsets, ticket);
    k_edge<<<N_EDGES / 64, 256, 0, stream>>>(feats_edge, ce, ssrc, sdst, src, dst, rank, offsets, es);
    k_gather<<<N_NODES / 4, 256, 0, stream>>>(offsets, es, zb, h);
}